// Round 14
// baseline (66.959 us; speedup 1.0000x reference)
//
#include <hip/hip_runtime.h>
#include <hip/hip_bf16.h>

#define B_   8
#define LQ_  128
#define LM_  512
#define D_   512
#define H_   256
#define MASKVAL -1e24f
#define PRESCALE 2.88539008177792681f  // 2*log2(e): exp2(PRESCALE*x) = e^(2x)

typedef __attribute__((ext_vector_type(8))) short bf16x8;
typedef __attribute__((ext_vector_type(4))) float f32x4;

__device__ __forceinline__ ushort f2bf(float x) {
    return __builtin_bit_cast(ushort, __float2bfloat16(x));
}

__device__ __forceinline__ float rdlane(float x, int l) {
    return __builtin_bit_cast(float, __builtin_amdgcn_readlane(__builtin_bit_cast(int, x), l));
}

// ---------------- MFMA projection GEMM (bf16 inputs, f32 accum) ----------------
// qp: row-major [1024][256], holds Eq = exp2(PRESCALE*(q@Wq+bq))
// kT4: h-packed transpose [64 h4][4096 m][4 c], holds Ek
#define PBM 32
#define PBN 32
#define PBK 64
#define PLDK 88

__global__ __launch_bounds__(256) void proj_mfma(
    const float* __restrict__ query, const float* __restrict__ memory,
    const float* __restrict__ Wq, const float* __restrict__ Wm,
    const float* __restrict__ bq,
    float* __restrict__ qp, float* __restrict__ kT4)
{
    __shared__ ushort As[PBM][PLDK];
    __shared__ ushort Bs[PBN][PLDK];
    __shared__ float  T[PBM][33];      // kp transpose bounce

    const int mtile = blockIdx.x % 160;
    const int ntile = blockIdx.x / 160;
    const int n0 = ntile * PBN;
    const bool is_q = (mtile < 32);
    const float* X = is_q ? (query  + (size_t)mtile * PBM * D_)
                          : (memory + (size_t)(mtile - 32) * PBM * D_);
    const float* W = is_q ? Wq : Wm;

    const int t = threadIdx.x;
    const int lane = t & 63, w = t >> 6;
    const int wm = (w & 1) * 16, wn = (w >> 1) * 16;
    const int ar  = t >> 4;
    const int akq = t & 15;
    const int frow = lane & 15;
    const int fkof = (lane >> 4) * 8;

    f32x4 acc = {0.f, 0.f, 0.f, 0.f};

    for (int k0 = 0; k0 < D_; k0 += PBK) {
#pragma unroll
        for (int p = 0; p < 2; ++p) {
            const int row = ar + p * 16;
            const float4 x4 = *(const float4*)(X + (size_t)row * D_ + k0 + akq * 4);
            ushort4 u4;
            u4.x = f2bf(x4.x); u4.y = f2bf(x4.y); u4.z = f2bf(x4.z); u4.w = f2bf(x4.w);
            *(ushort4*)&As[row][akq * 4] = u4;
        }
#pragma unroll
        for (int p = 0; p < 2; ++p) {
            const int L  = t + p * 256;
            const int kk = L >> 3;
            const int f4 = L & 7;
            const float4 w4 = *(const float4*)(W + (size_t)(k0 + kk) * H_ + n0 + f4 * 4);
            Bs[f4 * 4 + 0][kk] = f2bf(w4.x);
            Bs[f4 * 4 + 1][kk] = f2bf(w4.y);
            Bs[f4 * 4 + 2][kk] = f2bf(w4.z);
            Bs[f4 * 4 + 3][kk] = f2bf(w4.w);
        }
        __syncthreads();
#pragma unroll
        for (int ks = 0; ks < PBK; ks += 32) {
            bf16x8 a = *(const bf16x8*)&As[wm + frow][ks + fkof];
            bf16x8 b = *(const bf16x8*)&Bs[wn + frow][ks + fkof];
            acc = __builtin_amdgcn_mfma_f32_16x16x32_bf16(a, b, acc, 0, 0, 0);
        }
        __syncthreads();
    }

    const int lane16 = lane & 15;
    const int rloc = wm + (lane >> 4) * 4;
    if (is_q) {
        const int col = n0 + wn + lane16;
        const float bias = bq[col];
        float* out = qp + (size_t)mtile * PBM * H_;
#pragma unroll
        for (int r = 0; r < 4; ++r)
            out[(size_t)(rloc + r) * H_ + col] =
                __builtin_amdgcn_exp2f((acc[r] + bias) * PRESCALE);
    } else {
#pragma unroll
        for (int r = 0; r < 4; ++r)
            T[rloc + r][wn + lane16] = __builtin_amdgcn_exp2f(acc[r] * PRESCALE);
        __syncthreads();
        const int m_local = t & 31;
        const int hq = t >> 5;
        const int h0 = hq * 4;
        float4 o;
        o.x = T[m_local][h0 + 0];
        o.y = T[m_local][h0 + 1];
        o.z = T[m_local][h0 + 2];
        o.w = T[m_local][h0 + 3];
        float* dst = kT4 + ((size_t)(n0 / 4 + hq) * 4096 + (size_t)(mtile - 32) * 32 + m_local) * 4;
        *(float4*)dst = o;
    }
}

// ---------------- fused score/softmax/PV ----------------
// 256 blocks x 512 thr. Block = (b, 4 q).
// Phase 1: lane = m, coalesced kT4 loads, uniform q/v (s_load), QUAD rcp.
// Phase 3: weights delivered via v_readlane from per-wave VGPRs (ZERO LDS
// traffic in the hot loop — the LDS-broadcast pipe was the 25 us invariant).
// Masked m have weight exactly 0 (exp2(-huge) flushes) -> no compaction.
__global__ __launch_bounds__(512, 2) void attn_kernel(
    const float* __restrict__ qp,      // [1024][256] = Eq (row-major)
    const float* __restrict__ kT4,     // [64][4096][4] = Ek (h-packed T)
    const float* __restrict__ memory,  // [8][512][512]
    const int*   __restrict__ mask,    // [8][512]
    const float* __restrict__ v,       // [256]
    float* __restrict__ out_wm,        // [1024][512]
    float* __restrict__ out_w)         // [1024][512]
{
    __shared__ float scores[4][512];   // 8 KB

    const int t = threadIdx.x;
    const int b  = blockIdx.x & 7;     // all blocks of batch b -> XCD b
    const int qg = blockIdx.x >> 3;    // 0..31
    const int rowbase = b * LQ_ + qg * 4;
    const int w = t >> 6, lane = t & 63;

    // ---- phase 1: scores[q][m] = -2 * sum_h v[h] * rcp(Eq*Ek + 1) ----
    {
        const int m = w * 64 + lane;
        const float* kbase = kT4 + ((size_t)b * 512 + m) * 4;
        const float* q0r = qp + (size_t)(rowbase + 0) * 256;   // uniform -> s_load
        const float* q1r = qp + (size_t)(rowbase + 1) * 256;
        const float* q2r = qp + (size_t)(rowbase + 2) * 256;
        const float* q3r = qp + (size_t)(rowbase + 3) * 256;
        float acc0 = 0.f, acc1 = 0.f, acc2 = 0.f, acc3 = 0.f;
#define QUAD(ACC, SQ, K, SV) { \
        const float u_ = fmaf(SQ.x, K.x, 1.f); \
        const float w_ = fmaf(SQ.y, K.y, 1.f); \
        const float y_ = fmaf(SQ.z, K.z, 1.f); \
        const float z_ = fmaf(SQ.w, K.w, 1.f); \
        const float d12_ = u_ * w_, d34_ = y_ * z_; \
        const float n12_ = fmaf(SV.y, u_, SV.x * w_); \
        const float n34_ = fmaf(SV.w, y_, SV.z * z_); \
        const float N_ = fmaf(n12_, d34_, n34_ * d12_); \
        ACC = fmaf(N_, __builtin_amdgcn_rcpf(d12_ * d34_), ACC); }
#pragma unroll 4
        for (int h4 = 0; h4 < 64; ++h4) {
            const float4 k4 = *(const float4*)(kbase + (size_t)h4 * 16384);
            const float4 sv = *(const float4*)(v   + h4 * 4);
            const float4 s0 = *(const float4*)(q0r + h4 * 4);
            const float4 s1 = *(const float4*)(q1r + h4 * 4);
            const float4 s2 = *(const float4*)(q2r + h4 * 4);
            const float4 s3 = *(const float4*)(q3r + h4 * 4);
            QUAD(acc0, s0, k4, sv)
            QUAD(acc1, s1, k4, sv)
            QUAD(acc2, s2, k4, sv)
            QUAD(acc3, s3, k4, sv)
        }
#undef QUAD
        scores[0][m] = -2.f * acc0;
        scores[1][m] = -2.f * acc1;
        scores[2][m] = -2.f * acc2;
        scores[3][m] = -2.f * acc3;
    }
    __syncthreads();

    // ---- phase 2: softmax per q (waves 0..3); masked -> weight exactly 0 ----
    if (w < 4) {
        const int q = w, row = rowbase + q;
        float s[8], e[8];
        float mx = -INFINITY;
#pragma unroll
        for (int k = 0; k < 8; ++k) {
            const int m = lane + 64 * k;
            s[k] = mask[b * 512 + m] ? MASKVAL : scores[q][m];
            mx = fmaxf(mx, s[k]);
        }
#pragma unroll
        for (int off = 32; off >= 1; off >>= 1) mx = fmaxf(mx, __shfl_xor(mx, off));
        float sum = 0.0f;
#pragma unroll
        for (int k = 0; k < 8; ++k) {
            e[k] = __builtin_amdgcn_exp2f((s[k] - mx) * 1.44269504088896341f);
            sum += e[k];
        }
#pragma unroll
        for (int off = 32; off >= 1; off >>= 1) sum += __shfl_xor(sum, off);
        const float rs = __builtin_amdgcn_rcpf(sum);
#pragma unroll
        for (int k = 0; k < 8; ++k) {
            const float wt = e[k] * rs;
            scores[q][lane + 64 * k] = wt;
            out_w[(size_t)row * 512 + lane + 64 * k] = wt;
        }
    }
    __syncthreads();

    // ---- phase 3: weighted_memory via readlane-broadcast weights ----
    {
        const int dd = (w << 6) + lane;          // this wave's d column
        const float* mb = memory + (size_t)b * 512 * 512 + dd;
        // stage all 4 q-weight rows into registers: wq[q][r] = w[q][r*64+lane]
        float wq0[8], wq1[8], wq2[8], wq3[8];
#pragma unroll
        for (int r = 0; r < 8; ++r) {
            wq0[r] = scores[0][r * 64 + lane];
            wq1[r] = scores[1][r * 64 + lane];
            wq2[r] = scores[2][r * 64 + lane];
            wq3[r] = scores[3][r * 64 + lane];
        }
        float a0 = 0.f, a1 = 0.f, a2 = 0.f, a3 = 0.f;
#pragma unroll
        for (int r = 0; r < 8; ++r) {
            const float* mbr = mb + (size_t)r * 64 * 512;
#pragma unroll 4
            for (int ml = 0; ml < 64; ++ml) {
                const float vm = mbr[(size_t)ml * 512];
                a0 = fmaf(rdlane(wq0[r], ml), vm, a0);
                a1 = fmaf(rdlane(wq1[r], ml), vm, a1);
                a2 = fmaf(rdlane(wq2[r], ml), vm, a2);
                a3 = fmaf(rdlane(wq3[r], ml), vm, a3);
            }
        }
        out_wm[(size_t)(rowbase + 0) * 512 + dd] = a0;
        out_wm[(size_t)(rowbase + 1) * 512 + dd] = a1;
        out_wm[(size_t)(rowbase + 2) * 512 + dd] = a2;
        out_wm[(size_t)(rowbase + 3) * 512 + dd] = a3;
    }
}

extern "C" void kernel_launch(void* const* d_in, const int* in_sizes, int n_in,
                              void* d_out, int out_size, void* d_ws, size_t ws_size,
                              hipStream_t stream) {
    const float* query  = (const float*)d_in[0];
    const float* memory = (const float*)d_in[1];
    const int*   mask   = (const int*)  d_in[2];
    const float* Wq     = (const float*)d_in[3];
    const float* bq     = (const float*)d_in[4];
    const float* Wm     = (const float*)d_in[5];
    const float* v      = (const float*)d_in[6];

    float* out_wm = (float*)d_out;                         // [1024][512]
    float* out_w  = out_wm + (size_t)B_ * LQ_ * D_;        // [1024][512]

    float* qp  = (float*)d_ws;                             // [1024][256] = Eq
    float* kT4 = qp + (size_t)B_ * LQ_ * H_;               // [64][4096][4] = Ek

    hipLaunchKernelGGL(proj_mfma, dim3(160 * (H_ / PBN)), dim3(256), 0, stream,
                       query, memory, Wq, Wm, bq, qp, kT4);
    hipLaunchKernelGGL(attn_kernel, dim3(B_ * (LQ_ / 4)), dim3(512), 0, stream,
                       qp, kT4, memory, mask, v, out_wm, out_w);
}

// Round 15
// 44.070 us; speedup vs baseline: 1.5194x; 1.5194x over previous
//
#include <hip/hip_runtime.h>
#include <hip/hip_bf16.h>

#define B_   8
#define LQ_  128
#define LM_  512
#define D_   512
#define H_   256
#define MASKVAL -1e24f
#define PRESCALE 2.88539008177792681f  // 2*log2(e): exp2(PRESESCALE*x) = e^(2x)

typedef __attribute__((ext_vector_type(8))) short bf16x8;
typedef __attribute__((ext_vector_type(4))) float f32x4;

__device__ __forceinline__ ushort f2bf(float x) {
    return __builtin_bit_cast(ushort, __float2bfloat16(x));
}

// ---------------- MFMA projection GEMM (bf16 inputs, f32 accum) ----------------
// qp: row-major [1024][256], holds Eq = exp2(PRESCALE*(q@Wq+bq))
// kT4: h-packed transpose [64 h4][4096 m][4 c], holds Ek
#define PBM 32
#define PBN 32
#define PBK 64
#define PLDK 88

__global__ __launch_bounds__(256) void proj_mfma(
    const float* __restrict__ query, const float* __restrict__ memory,
    const float* __restrict__ Wq, const float* __restrict__ Wm,
    const float* __restrict__ bq,
    float* __restrict__ qp, float* __restrict__ kT4)
{
    __shared__ ushort As[PBM][PLDK];
    __shared__ ushort Bs[PBN][PLDK];
    __shared__ float  T[PBM][33];

    const int mtile = blockIdx.x % 160;
    const int ntile = blockIdx.x / 160;
    const int n0 = ntile * PBN;
    const bool is_q = (mtile < 32);
    const float* X = is_q ? (query  + (size_t)mtile * PBM * D_)
                          : (memory + (size_t)(mtile - 32) * PBM * D_);
    const float* W = is_q ? Wq : Wm;

    const int t = threadIdx.x;
    const int lane = t & 63, w = t >> 6;
    const int wm = (w & 1) * 16, wn = (w >> 1) * 16;
    const int ar  = t >> 4;
    const int akq = t & 15;
    const int frow = lane & 15;
    const int fkof = (lane >> 4) * 8;

    f32x4 acc = {0.f, 0.f, 0.f, 0.f};

    for (int k0 = 0; k0 < D_; k0 += PBK) {
#pragma unroll
        for (int p = 0; p < 2; ++p) {
            const int row = ar + p * 16;
            const float4 x4 = *(const float4*)(X + (size_t)row * D_ + k0 + akq * 4);
            ushort4 u4;
            u4.x = f2bf(x4.x); u4.y = f2bf(x4.y); u4.z = f2bf(x4.z); u4.w = f2bf(x4.w);
            *(ushort4*)&As[row][akq * 4] = u4;
        }
#pragma unroll
        for (int p = 0; p < 2; ++p) {
            const int L  = t + p * 256;
            const int kk = L >> 3;
            const int f4 = L & 7;
            const float4 w4 = *(const float4*)(W + (size_t)(k0 + kk) * H_ + n0 + f4 * 4);
            Bs[f4 * 4 + 0][kk] = f2bf(w4.x);
            Bs[f4 * 4 + 1][kk] = f2bf(w4.y);
            Bs[f4 * 4 + 2][kk] = f2bf(w4.z);
            Bs[f4 * 4 + 3][kk] = f2bf(w4.w);
        }
        __syncthreads();
#pragma unroll
        for (int ks = 0; ks < PBK; ks += 32) {
            bf16x8 a = *(const bf16x8*)&As[wm + frow][ks + fkof];
            bf16x8 b = *(const bf16x8*)&Bs[wn + frow][ks + fkof];
            acc = __builtin_amdgcn_mfma_f32_16x16x32_bf16(a, b, acc, 0, 0, 0);
        }
        __syncthreads();
    }

    const int lane16 = lane & 15;
    const int rloc = wm + (lane >> 4) * 4;
    if (is_q) {
        const int col = n0 + wn + lane16;
        const float bias = bq[col];
        float* out = qp + (size_t)mtile * PBM * H_;
#pragma unroll
        for (int r = 0; r < 4; ++r)
            out[(size_t)(rloc + r) * H_ + col] =
                __builtin_amdgcn_exp2f((acc[r] + bias) * PRESCALE);
    } else {
#pragma unroll
        for (int r = 0; r < 4; ++r)
            T[rloc + r][wn + lane16] = __builtin_amdgcn_exp2f(acc[r] * PRESCALE);
        __syncthreads();
        const int m_local = t & 31;
        const int hq = t >> 5;
        const int h0 = hq * 4;
        float4 o;
        o.x = T[m_local][h0 + 0];
        o.y = T[m_local][h0 + 1];
        o.z = T[m_local][h0 + 2];
        o.w = T[m_local][h0 + 3];
        float* dst = kT4 + ((size_t)(n0 / 4 + hq) * 4096 + (size_t)(mtile - 32) * 32 + m_local) * 4;
        *(float4*)dst = o;
    }
}

// ---------------- scores + softmax ----------------
// 256 blocks x 512 thr. Block = (b, 4 q). Phase 1: lane = m (coalesced kT4,
// uniform q/v via s_load, QUAD = 4 sigmoids per rcp). Softmax writes out_w
// (f32, required output) and wbf (bf16 shadow for the MFMA PV GEMM).
// Masked m get weight exactly 0 -> PV needs no mask/compaction.
__global__ __launch_bounds__(512, 2) void score_softmax(
    const float* __restrict__ qp,      // [1024][256] = Eq
    const float* __restrict__ kT4,     // [64][4096][4] = Ek
    const int*   __restrict__ mask,    // [8][512]
    const float* __restrict__ v,       // [256]
    float* __restrict__ out_w,         // [1024][512]
    ushort* __restrict__ wbf)          // [1024][512] bf16 weights
{
    __shared__ float scores[4][512];

    const int t = threadIdx.x;
    const int b  = blockIdx.x & 7;
    const int qg = blockIdx.x >> 3;
    const int rowbase = b * LQ_ + qg * 4;
    const int w = t >> 6, lane = t & 63;

    {
        const int m = t;               // 512 threads = 512 m
        const float* kbase = kT4 + ((size_t)b * 512 + m) * 4;
        const float* q0r = qp + (size_t)(rowbase + 0) * 256;
        const float* q1r = qp + (size_t)(rowbase + 1) * 256;
        const float* q2r = qp + (size_t)(rowbase + 2) * 256;
        const float* q3r = qp + (size_t)(rowbase + 3) * 256;
        float acc0 = 0.f, acc1 = 0.f, acc2 = 0.f, acc3 = 0.f;
#define QUAD(ACC, SQ, K, SV) { \
        const float u_ = fmaf(SQ.x, K.x, 1.f); \
        const float w_ = fmaf(SQ.y, K.y, 1.f); \
        const float y_ = fmaf(SQ.z, K.z, 1.f); \
        const float z_ = fmaf(SQ.w, K.w, 1.f); \
        const float d12_ = u_ * w_, d34_ = y_ * z_; \
        const float n12_ = fmaf(SV.y, u_, SV.x * w_); \
        const float n34_ = fmaf(SV.w, y_, SV.z * z_); \
        const float N_ = fmaf(n12_, d34_, n34_ * d12_); \
        ACC = fmaf(N_, __builtin_amdgcn_rcpf(d12_ * d34_), ACC); }
#pragma unroll 4
        for (int h4 = 0; h4 < 64; ++h4) {
            const float4 k4 = *(const float4*)(kbase + (size_t)h4 * 16384);
            const float4 sv = *(const float4*)(v   + h4 * 4);
            const float4 s0 = *(const float4*)(q0r + h4 * 4);
            const float4 s1 = *(const float4*)(q1r + h4 * 4);
            const float4 s2 = *(const float4*)(q2r + h4 * 4);
            const float4 s3 = *(const float4*)(q3r + h4 * 4);
            QUAD(acc0, s0, k4, sv)
            QUAD(acc1, s1, k4, sv)
            QUAD(acc2, s2, k4, sv)
            QUAD(acc3, s3, k4, sv)
        }
#undef QUAD
        scores[0][m] = -2.f * acc0;
        scores[1][m] = -2.f * acc1;
        scores[2][m] = -2.f * acc2;
        scores[3][m] = -2.f * acc3;
    }
    __syncthreads();

    if (w < 4) {
        const int q = w, row = rowbase + q;
        float s[8], e[8];
        float mx = -INFINITY;
#pragma unroll
        for (int k = 0; k < 8; ++k) {
            const int m = lane + 64 * k;
            s[k] = mask[b * 512 + m] ? MASKVAL : scores[q][m];
            mx = fmaxf(mx, s[k]);
        }
#pragma unroll
        for (int off = 32; off >= 1; off >>= 1) mx = fmaxf(mx, __shfl_xor(mx, off));
        float sum = 0.0f;
#pragma unroll
        for (int k = 0; k < 8; ++k) {
            e[k] = __builtin_amdgcn_exp2f((s[k] - mx) * 1.44269504088896341f);
            sum += e[k];
        }
#pragma unroll
        for (int off = 32; off >= 1; off >>= 1) sum += __shfl_xor(sum, off);
        const float rs = __builtin_amdgcn_rcpf(sum);
#pragma unroll
        for (int k = 0; k < 8; ++k) {
            const int m = lane + 64 * k;
            const float wt = e[k] * rs;
            out_w[(size_t)row * 512 + m] = wt;
            wbf[(size_t)row * 512 + m] = f2bf(wt);
        }
    }
}

// ---------------- PV via MFMA: out_wm[q][d] = sum_m w[q][m]*mem[m][d] ----------------
// Per b: [128 q x 512 m] (bf16) x [512 m x 512 d] (f32->bf16 staged).
// 512 blocks (b XCD-swizzled), 256 thr, 32x32 tile — proj_mfma clone.
__global__ __launch_bounds__(256) void pv_mfma(
    const ushort* __restrict__ wbf,    // [1024][512] bf16
    const float* __restrict__ memory,  // [8][512][512]
    float* __restrict__ out_wm)        // [1024][512]
{
    __shared__ ushort As[PBM][PLDK];
    __shared__ ushort Bs[PBN][PLDK];

    const int b    = blockIdx.x & 7;
    const int rest = blockIdx.x >> 3;  // 0..63
    const int mt   = rest & 3;         // q-tile 0..3
    const int nt   = rest >> 2;        // d-tile 0..15
    const int n0   = nt * PBN;
    const ushort* A = wbf + ((size_t)b * LQ_ + mt * PBM) * 512;
    const float*  Bm = memory + (size_t)b * 512 * 512;

    const int t = threadIdx.x;
    const int lane = t & 63, w = t >> 6;
    const int wm = (w & 1) * 16, wn = (w >> 1) * 16;
    const int ar  = t >> 4;
    const int akq = t & 15;
    const int frow = lane & 15;
    const int fkof = (lane >> 4) * 8;

    f32x4 acc = {0.f, 0.f, 0.f, 0.f};

    for (int k0 = 0; k0 < 512; k0 += PBK) {
#pragma unroll
        for (int p = 0; p < 2; ++p) {
            const int row = ar + p * 16;
            *(ushort4*)&As[row][akq * 4] =
                *(const ushort4*)(A + (size_t)row * 512 + k0 + akq * 4);
        }
#pragma unroll
        for (int p = 0; p < 2; ++p) {
            const int L  = t + p * 256;
            const int kk = L >> 3;
            const int f4 = L & 7;
            const float4 w4 = *(const float4*)(Bm + (size_t)(k0 + kk) * 512 + n0 + f4 * 4);
            Bs[f4 * 4 + 0][kk] = f2bf(w4.x);
            Bs[f4 * 4 + 1][kk] = f2bf(w4.y);
            Bs[f4 * 4 + 2][kk] = f2bf(w4.z);
            Bs[f4 * 4 + 3][kk] = f2bf(w4.w);
        }
        __syncthreads();
#pragma unroll
        for (int ks = 0; ks < PBK; ks += 32) {
            bf16x8 a = *(const bf16x8*)&As[wm + frow][ks + fkof];
            bf16x8 b2 = *(const bf16x8*)&Bs[wn + frow][ks + fkof];
            acc = __builtin_amdgcn_mfma_f32_16x16x32_bf16(a, b2, acc, 0, 0, 0);
        }
        __syncthreads();
    }

    const int col  = n0 + wn + (lane & 15);
    const int rloc = wm + (lane >> 4) * 4;
    float* out = out_wm + ((size_t)b * LQ_ + mt * PBM) * 512;
#pragma unroll
    for (int r = 0; r < 4; ++r)
        out[(size_t)(rloc + r) * 512 + col] = acc[r];
}

extern "C" void kernel_launch(void* const* d_in, const int* in_sizes, int n_in,
                              void* d_out, int out_size, void* d_ws, size_t ws_size,
                              hipStream_t stream) {
    const float* query  = (const float*)d_in[0];
    const float* memory = (const float*)d_in[1];
    const int*   mask   = (const int*)  d_in[2];
    const float* Wq     = (const float*)d_in[3];
    const float* bq     = (const float*)d_in[4];
    const float* Wm     = (const float*)d_in[5];
    const float* v      = (const float*)d_in[6];

    float* out_wm = (float*)d_out;                         // [1024][512]
    float* out_w  = out_wm + (size_t)B_ * LQ_ * D_;        // [1024][512]

    float*  qp  = (float*)d_ws;                            // [1024][256] = Eq
    float*  kT4 = qp + (size_t)B_ * LQ_ * H_;              // [64][4096][4] = Ek
    ushort* wbf = (ushort*)(kT4 + (size_t)64 * 4096 * 4);  // [1024][512] bf16

    hipLaunchKernelGGL(proj_mfma, dim3(160 * (H_ / PBN)), dim3(256), 0, stream,
                       query, memory, Wq, Wm, bq, qp, kT4);
    hipLaunchKernelGGL(score_softmax, dim3(B_ * (LQ_ / 4)), dim3(512), 0, stream,
                       qp, kT4, mask, v, out_w, wbf);
    hipLaunchKernelGGL(pv_mfma, dim3(8 * 64), dim3(256), 0, stream,
                       wbf, memory, out_wm);
}

// Round 16
// 40.686 us; speedup vs baseline: 1.6458x; 1.0832x over previous
//
#include <hip/hip_runtime.h>
#include <hip/hip_bf16.h>

#define B_   8
#define LQ_  128
#define LM_  512
#define D_   512
#define H_   256
#define MASKVAL -1e24f
#define PRESCALE 2.88539008177792681f  // 2*log2(e): exp2(PRESCALE*x) = e^(2x)

typedef __attribute__((ext_vector_type(8))) short bf16x8;
typedef __attribute__((ext_vector_type(4))) float f32x4;

__device__ __forceinline__ ushort f2bf(float x) {
    return __builtin_bit_cast(ushort, __float2bfloat16(x));
}

// ---------------- MFMA projection GEMM (bf16 inputs, f32 accum) ----------------
// qp: row-major [1024][256], holds Eq = exp2(PRESCALE*(q@Wq+bq))
// kT4: h-packed transpose [64 h4][4096 m][4 c], holds Ek
#define PBM 32
#define PBN 32
#define PBK 64
#define PLDK 88

__global__ __launch_bounds__(256) void proj_mfma(
    const float* __restrict__ query, const float* __restrict__ memory,
    const float* __restrict__ Wq, const float* __restrict__ Wm,
    const float* __restrict__ bq,
    float* __restrict__ qp, float* __restrict__ kT4)
{
    __shared__ ushort As[PBM][PLDK];
    __shared__ ushort Bs[PBN][PLDK];
    __shared__ float  T[PBM][33];

    const int mtile = blockIdx.x % 160;
    const int ntile = blockIdx.x / 160;
    const int n0 = ntile * PBN;
    const bool is_q = (mtile < 32);
    const float* X = is_q ? (query  + (size_t)mtile * PBM * D_)
                          : (memory + (size_t)(mtile - 32) * PBM * D_);
    const float* W = is_q ? Wq : Wm;

    const int t = threadIdx.x;
    const int lane = t & 63, w = t >> 6;
    const int wm = (w & 1) * 16, wn = (w >> 1) * 16;
    const int ar  = t >> 4;
    const int akq = t & 15;
    const int frow = lane & 15;
    const int fkof = (lane >> 4) * 8;

    f32x4 acc = {0.f, 0.f, 0.f, 0.f};

    for (int k0 = 0; k0 < D_; k0 += PBK) {
#pragma unroll
        for (int p = 0; p < 2; ++p) {
            const int row = ar + p * 16;
            const float4 x4 = *(const float4*)(X + (size_t)row * D_ + k0 + akq * 4);
            ushort4 u4;
            u4.x = f2bf(x4.x); u4.y = f2bf(x4.y); u4.z = f2bf(x4.z); u4.w = f2bf(x4.w);
            *(ushort4*)&As[row][akq * 4] = u4;
        }
#pragma unroll
        for (int p = 0; p < 2; ++p) {
            const int L  = t + p * 256;
            const int kk = L >> 3;
            const int f4 = L & 7;
            const float4 w4 = *(const float4*)(W + (size_t)(k0 + kk) * H_ + n0 + f4 * 4);
            Bs[f4 * 4 + 0][kk] = f2bf(w4.x);
            Bs[f4 * 4 + 1][kk] = f2bf(w4.y);
            Bs[f4 * 4 + 2][kk] = f2bf(w4.z);
            Bs[f4 * 4 + 3][kk] = f2bf(w4.w);
        }
        __syncthreads();
#pragma unroll
        for (int ks = 0; ks < PBK; ks += 32) {
            bf16x8 a = *(const bf16x8*)&As[wm + frow][ks + fkof];
            bf16x8 b = *(const bf16x8*)&Bs[wn + frow][ks + fkof];
            acc = __builtin_amdgcn_mfma_f32_16x16x32_bf16(a, b, acc, 0, 0, 0);
        }
        __syncthreads();
    }

    const int lane16 = lane & 15;
    const int rloc = wm + (lane >> 4) * 4;
    if (is_q) {
        const int col = n0 + wn + lane16;
        const float bias = bq[col];
        float* out = qp + (size_t)mtile * PBM * H_;
#pragma unroll
        for (int r = 0; r < 4; ++r)
            out[(size_t)(rloc + r) * H_ + col] =
                __builtin_amdgcn_exp2f((acc[r] + bias) * PRESCALE);
    } else {
#pragma unroll
        for (int r = 0; r < 4; ++r)
            T[rloc + r][wn + lane16] = __builtin_amdgcn_exp2f(acc[r] * PRESCALE);
        __syncthreads();
        const int m_local = t & 31;
        const int hq = t >> 5;
        const int h0 = hq * 4;
        float4 o;
        o.x = T[m_local][h0 + 0];
        o.y = T[m_local][h0 + 1];
        o.z = T[m_local][h0 + 2];
        o.w = T[m_local][h0 + 3];
        float* dst = kT4 + ((size_t)(n0 / 4 + hq) * 4096 + (size_t)(mtile - 32) * 32 + m_local) * 4;
        *(float4*)dst = o;
    }
}

// ---------------- scores + softmax ----------------
// 512 blocks x 512 thr. Block = (b, 2 q) -> 2 blocks/CU, 4 waves/SIMD:
// double the latency hiding of the R15 version (which was 1 block/CU and
// latency-bound on kT4 streaming + uniform q/v loads).
__global__ __launch_bounds__(512, 4) void score_softmax(
    const float* __restrict__ qp,      // [1024][256] = Eq
    const float* __restrict__ kT4,     // [64][4096][4] = Ek
    const int*   __restrict__ mask,    // [8][512]
    const float* __restrict__ v,       // [256]
    float* __restrict__ out_w,         // [1024][512]
    ushort* __restrict__ wbf)          // [1024][512] bf16 weights
{
    __shared__ float scores[2][512];

    const int t = threadIdx.x;
    const int b  = blockIdx.x & 7;
    const int qg = blockIdx.x >> 3;    // 0..63
    const int rowbase = b * LQ_ + qg * 2;
    const int w = t >> 6, lane = t & 63;

    {
        const int m = t;               // 512 threads = 512 m
        const float* kbase = kT4 + ((size_t)b * 512 + m) * 4;
        const float* q0r = qp + (size_t)(rowbase + 0) * 256;
        const float* q1r = qp + (size_t)(rowbase + 1) * 256;
        float acc0 = 0.f, acc1 = 0.f;
#define QUAD(ACC, SQ, K, SV) { \
        const float u_ = fmaf(SQ.x, K.x, 1.f); \
        const float w_ = fmaf(SQ.y, K.y, 1.f); \
        const float y_ = fmaf(SQ.z, K.z, 1.f); \
        const float z_ = fmaf(SQ.w, K.w, 1.f); \
        const float d12_ = u_ * w_, d34_ = y_ * z_; \
        const float n12_ = fmaf(SV.y, u_, SV.x * w_); \
        const float n34_ = fmaf(SV.w, y_, SV.z * z_); \
        const float N_ = fmaf(n12_, d34_, n34_ * d12_); \
        ACC = fmaf(N_, __builtin_amdgcn_rcpf(d12_ * d34_), ACC); }
#pragma unroll 4
        for (int h4 = 0; h4 < 64; ++h4) {
            const float4 k4 = *(const float4*)(kbase + (size_t)h4 * 16384);
            const float4 sv = *(const float4*)(v   + h4 * 4);
            const float4 s0 = *(const float4*)(q0r + h4 * 4);
            const float4 s1 = *(const float4*)(q1r + h4 * 4);
            QUAD(acc0, s0, k4, sv)
            QUAD(acc1, s1, k4, sv)
        }
#undef QUAD
        scores[0][m] = -2.f * acc0;
        scores[1][m] = -2.f * acc1;
    }
    __syncthreads();

    if (w < 2) {
        const int q = w, row = rowbase + q;
        float s[8], e[8];
        float mx = -INFINITY;
#pragma unroll
        for (int k = 0; k < 8; ++k) {
            const int m = lane + 64 * k;
            s[k] = mask[b * 512 + m] ? MASKVAL : scores[q][m];
            mx = fmaxf(mx, s[k]);
        }
#pragma unroll
        for (int off = 32; off >= 1; off >>= 1) mx = fmaxf(mx, __shfl_xor(mx, off));
        float sum = 0.0f;
#pragma unroll
        for (int k = 0; k < 8; ++k) {
            e[k] = __builtin_amdgcn_exp2f((s[k] - mx) * 1.44269504088896341f);
            sum += e[k];
        }
#pragma unroll
        for (int off = 32; off >= 1; off >>= 1) sum += __shfl_xor(sum, off);
        const float rs = __builtin_amdgcn_rcpf(sum);
#pragma unroll
        for (int k = 0; k < 8; ++k) {
            const int m = lane + 64 * k;
            const float wt = e[k] * rs;
            out_w[(size_t)row * 512 + m] = wt;
            wbf[(size_t)row * 512 + m] = f2bf(wt);
        }
    }
}

// ---------------- PV via MFMA: out_wm[q][d] = sum_m w[q][m]*mem[m][d] ----------------
__global__ __launch_bounds__(256) void pv_mfma(
    const ushort* __restrict__ wbf,    // [1024][512] bf16
    const float* __restrict__ memory,  // [8][512][512]
    float* __restrict__ out_wm)        // [1024][512]
{
    __shared__ ushort As[PBM][PLDK];
    __shared__ ushort Bs[PBN][PLDK];

    const int b    = blockIdx.x & 7;
    const int rest = blockIdx.x >> 3;  // 0..63
    const int mt   = rest & 3;         // q-tile 0..3
    const int nt   = rest >> 2;        // d-tile 0..15
    const int n0   = nt * PBN;
    const ushort* A = wbf + ((size_t)b * LQ_ + mt * PBM) * 512;
    const float*  Bm = memory + (size_t)b * 512 * 512;

    const int t = threadIdx.x;
    const int lane = t & 63, w = t >> 6;
    const int wm = (w & 1) * 16, wn = (w >> 1) * 16;
    const int ar  = t >> 4;
    const int akq = t & 15;
    const int frow = lane & 15;
    const int fkof = (lane >> 4) * 8;

    f32x4 acc = {0.f, 0.f, 0.f, 0.f};

    for (int k0 = 0; k0 < 512; k0 += PBK) {
#pragma unroll
        for (int p = 0; p < 2; ++p) {
            const int row = ar + p * 16;
            *(ushort4*)&As[row][akq * 4] =
                *(const ushort4*)(A + (size_t)row * 512 + k0 + akq * 4);
        }
#pragma unroll
        for (int p = 0; p < 2; ++p) {
            const int L  = t + p * 256;
            const int kk = L >> 3;
            const int f4 = L & 7;
            const float4 w4 = *(const float4*)(Bm + (size_t)(k0 + kk) * 512 + n0 + f4 * 4);
            Bs[f4 * 4 + 0][kk] = f2bf(w4.x);
            Bs[f4 * 4 + 1][kk] = f2bf(w4.y);
            Bs[f4 * 4 + 2][kk] = f2bf(w4.z);
            Bs[f4 * 4 + 3][kk] = f2bf(w4.w);
        }
        __syncthreads();
#pragma unroll
        for (int ks = 0; ks < PBK; ks += 32) {
            bf16x8 a = *(const bf16x8*)&As[wm + frow][ks + fkof];
            bf16x8 b2 = *(const bf16x8*)&Bs[wn + frow][ks + fkof];
            acc = __builtin_amdgcn_mfma_f32_16x16x32_bf16(a, b2, acc, 0, 0, 0);
        }
        __syncthreads();
    }

    const int col  = n0 + wn + (lane & 15);
    const int rloc = wm + (lane >> 4) * 4;
    float* out = out_wm + ((size_t)b * LQ_ + mt * PBM) * 512;
#pragma unroll
    for (int r = 0; r < 4; ++r)
        out[(size_t)(rloc + r) * 512 + col] = acc[r];
}

extern "C" void kernel_launch(void* const* d_in, const int* in_sizes, int n_in,
                              void* d_out, int out_size, void* d_ws, size_t ws_size,
                              hipStream_t stream) {
    const float* query  = (const float*)d_in[0];
    const float* memory = (const float*)d_in[1];
    const int*   mask   = (const int*)  d_in[2];
    const float* Wq     = (const float*)d_in[3];
    const float* bq     = (const float*)d_in[4];
    const float* Wm     = (const float*)d_in[5];
    const float* v      = (const float*)d_in[6];

    float* out_wm = (float*)d_out;                         // [1024][512]
    float* out_w  = out_wm + (size_t)B_ * LQ_ * D_;        // [1024][512]

    float*  qp  = (float*)d_ws;                            // [1024][256] = Eq
    float*  kT4 = qp + (size_t)B_ * LQ_ * H_;              // [64][4096][4] = Ek
    ushort* wbf = (ushort*)(kT4 + (size_t)64 * 4096 * 4);  // [1024][512] bf16

    hipLaunchKernelGGL(proj_mfma, dim3(160 * (H_ / PBN)), dim3(256), 0, stream,
                       query, memory, Wq, Wm, bq, qp, kT4);
    hipLaunchKernelGGL(score_softmax, dim3(B_ * (LQ_ / 2)), dim3(512), 0, stream,
                       qp, kT4, mask, v, out_w, wbf);
    hipLaunchKernelGGL(pv_mfma, dim3(8 * 64), dim3(256), 0, stream,
                       wbf, memory, out_wm);
}